// Round 10
// baseline (197.007 us; speedup 1.0000x reference)
//
#include <hip/hip_runtime.h>

// SimpleRNN fused kernel for MI355X (gfx950).  B=32768, T=28, I=28, H=128, C=10.
//
// R16 = R15 (78.8 us: exp2-tanh + MFMA epilogue) x 32 batches per block.
// (Resubmission: previous round's bench died on container acquisition —
//  "MI355X container failed twice" — the kernel never executed.)
// Clean retest of R14's barrier-amortization with BOTH confounders removed:
//   - R14 had in-loop global x (per-step vmcnt wait, ~15 us, proven R11-vs-R7)
//     -> here x is LDS-staged in 10-step chunks (R13-proven stager, stride
//     324), restaged between step barriers at t=10 and t=20.
//   - R14 spilled (WRITE 43 MB) -> here persistent set stays 48 regs (W/U/
//     bias shared across 4 waves; n-tiling only adds acc+frag regs, peak
//     ~100 < 128 cap of (256,4)).
// Structure:
//   - Block = 256 thr / 4 waves owns 32 batches; wave w: h [32w,32w+32)
//     (2 m-tiles) x 2 n-tiles (batches 0-15, 16-31).  20 MFMA + 4 tanh4
//     per wave-step; ONE barrier per step for 32 batches (R15: per 16).
//   - Sbuf[2][32*132] = 16.9 KB + Xbuf[32*324] = 20.7 KB -> 37.6 KB ->
//     4 blocks/CU (same as R15).  Grid 1024 = B/32.
//   - exp2 tanh (R15-proven), bias-as-MFMA-C, MFMA epilogue on waves 0,1.
// Ledger (do not revisit): residency knobs (R11/R13), barrier-free state-in-
// regs (R8/R12), launch_bounds>4 (R10), pk-f32 asm tanh (R9), in-loop
// global x (R11/R14).
// Kill-criterion: dur >= 78 us with clean WRITE_SIZE => amortization dead on
// clean evidence; revert to R15 + MFMA chain-split.
//
// MFMA 16x16x32 bf16 layouts (m89/m91):
//   A[m=lane&15][k=(lane>>4)*8+j]  B[k=(lane>>4)*8+j][n=lane&15]
//   D[(lane>>4)*4+r][lane&15]

#define T_STEPS 28
#define S_STRIDE 132
#define X_STRIDE 324         // 10*32 + 4 pad (R13-proven bank residue)

typedef __attribute__((ext_vector_type(4))) float f32x4;
typedef __attribute__((ext_vector_type(8))) short short8;

#define MFMA16 __builtin_amdgcn_mfma_f32_16x16x32_bf16

__device__ __forceinline__ unsigned pack2(float lo, float hi) {
#if __has_builtin(__builtin_amdgcn_cvt_pk_bf16_f32)
  auto p = __builtin_amdgcn_cvt_pk_bf16_f32(lo, hi);   // RNE pack, 1 inst
  return __builtin_bit_cast(unsigned, p);
#else
  unsigned a = __builtin_bit_cast(unsigned, lo);
  a += 0x7FFFu + ((a >> 16) & 1u);
  unsigned b = __builtin_bit_cast(unsigned, hi);
  b += 0x7FFFu + ((b >> 16) & 1u);
  return (a >> 16) | (b & 0xFFFF0000u);
#endif
}

__device__ __forceinline__ short8 to_frag(f32x4 a, f32x4 b) {
  union { unsigned u[4]; short8 v; } r;
  r.u[0] = pack2(a[0], a[1]);
  r.u[1] = pack2(a[2], a[3]);
  r.u[2] = pack2(b[0], b[1]);
  r.u[3] = pack2(b[2], b[3]);
  return r.v;
}

__device__ __forceinline__ short8 load_frag64(const unsigned short* sp, int off) {
  // two b64 reads; measured conflict-free at the stride-132 pattern (R1..R15)
  union { uint2 d[2]; short8 v; } r;
  r.d[0] = *(const uint2*)(sp + off);
  r.d[1] = *(const uint2*)(sp + off + 4);
  return r.v;
}

__device__ __forceinline__ float fast_exp2(float a) {
#if __has_builtin(__builtin_amdgcn_exp2f)
  return __builtin_amdgcn_exp2f(a);   // v_exp_f32
#else
  return __exp2f(a);
#endif
}

// tanh(x) = 1 - 2/(1 + e^{2x}); e^{2x} = 2^(x * 2*log2(e)).  5 insts/elem,
// saturates naturally, err ~1e-6.  (R15-proven: -12 us vs Pade.)
__device__ __forceinline__ f32x4 tanh4(f32x4 z) {
  f32x4 t;
#pragma unroll
  for (int i = 0; i < 4; ++i) {
    float e = fast_exp2(z[i] * 2.885390081777927f);
    float r = __builtin_amdgcn_rcpf(1.0f + e);
    t[i] = __builtin_fmaf(r, -2.0f, 1.0f);
  }
  return t;
}

// Stage NT timesteps [t0, t0+NT) of this block's 32 x-rows into Xbuf (bf16,
// k-padded to 32).  Slot s (f32x4): row = s/(NT*7), tt, j.  16B-aligned.
template <int NT>
__device__ __forceinline__ void stage_chunk(const float* __restrict__ xblk,
                                            unsigned short* __restrict__ Xb,
                                            int tid, int t0) {
  constexpr int SLOTS = 32 * NT * 7;
  constexpr int ITERS = (SLOTS + 255) / 256;
  f32x4 xr[ITERS];
#pragma unroll
  for (int k = 0; k < ITERS; ++k) {
    const int s = tid + 256 * k;
    if (s < SLOTS) {
      const int row = s / (NT * 7), g = s - row * (NT * 7);
      const int tt = g / 7, j = g - tt * 7;
      xr[k] = *(const f32x4*)(xblk + row * 784 + (t0 + tt) * 28 + j * 4);
    }
  }
#pragma unroll
  for (int k = 0; k < ITERS; ++k) {
    const int s = tid + 256 * k;
    if (s < SLOTS) {
      const int row = s / (NT * 7), g = s - row * (NT * 7);
      const int tt = g / 7, j = g - tt * 7;
      uint2 d; d.x = pack2(xr[k][0], xr[k][1]); d.y = pack2(xr[k][2], xr[k][3]);
      *(uint2*)(Xb + row * X_STRIDE + tt * 32 + j * 4) = d;
      if (j == 0) {                       // zero k=28..31 once per (row,tt)
        uint2 zz; zz.x = 0u; zz.y = 0u;
        *(uint2*)(Xb + row * X_STRIDE + tt * 32 + 28) = zz;
      }
    }
  }
}

__global__ __launch_bounds__(256, 4) void rnn_fused(
    const float* __restrict__ x,  const float* __restrict__ Uw,
    const float* __restrict__ Ub, const float* __restrict__ Ww,
    const float* __restrict__ Wb, const float* __restrict__ Vw,
    const float* __restrict__ Vb, float* __restrict__ out) {
  __shared__ __align__(16) unsigned short Sbuf[2][32 * S_STRIDE];  // 16896 B
  __shared__ __align__(16) unsigned short Xbuf[32 * X_STRIDE];     // 20736 B

  const int tid  = threadIdx.x;
  const int w    = tid >> 6;
  const int lane = tid & 63;
  const int l15  = lane & 15;
  const int q    = lane >> 4;           // 0..3
  const int mrow = w * 32;              // h base for this wave (2 m-tiles)
  const int b0   = blockIdx.x * 32;

  const f32x4 zero4 = {0.f, 0.f, 0.f, 0.f};
  const float* xblk = x + (size_t)b0 * 784;

  // ---- prologue A: stage chunk 0 (t = 0..9) ----
  stage_chunk<10>(xblk, Xbuf, tid, 0);

  // ---- prologue B: persistent weight fragments (after staging regs die) ----
  short8 wfrag[2][4];   // [mt][kt]
  short8 ufrag[2];      // [mt], K=32 padded (k>=28 zeroed)
  f32x4  bias[2];       // Ub[h]+Wb[h] at D rows h = mrow + mt*16 + q*4 + r
#pragma unroll
  for (int mt = 0; mt < 2; ++mt) {
    const int h = mrow + mt * 16 + l15;
    const float* wp = Ww + h * 128 + q * 8;
#pragma unroll
    for (int kt = 0; kt < 4; ++kt) {
      wfrag[mt][kt] = to_frag(*(const f32x4*)wp, *(const f32x4*)(wp + 4));
      wp += 32;
    }
    const float* up = Uw + h * 28 + q * 8;
    f32x4 u0 = *(const f32x4*)up;
    f32x4 u1 = zero4;
    if (q < 3) u1 = *(const f32x4*)(up + 4);
    ufrag[mt] = to_frag(u0, u1);
    const int hb = mrow + mt * 16 + q * 4;
    bias[mt] = *(const f32x4*)(Wb + hb) + *(const f32x4*)(Ub + hb);
  }
  __syncthreads();   // Xbuf chunk 0 visible

  // n-tile bases: nt0 = batch rows 0-15 (l15), nt1 = rows 16-31 (16+l15)
  const int ro0 = l15 * S_STRIDE;
  const int ro1 = (16 + l15) * S_STRIDE;
  const int xo0 = l15 * X_STRIDE + q * 8;
  const int xo1 = (16 + l15) * X_STRIDE + q * 8;
  const int dcol = mrow + q * 4;
  f32x4 acc[2][2];                               // [mt][nt]

  // one recurrence step (reads Xbuf slot tt, Sbuf[t&1]; writes Sbuf[(t+1)&1])
  auto step = [&](int t, int tt) {
    short8 xf0 = load_frag64(&Xbuf[0], xo0 + tt * 32);
    short8 xf1 = load_frag64(&Xbuf[0], xo1 + tt * 32);
    const unsigned short* sb = &Sbuf[t & 1][0] + q * 8;

    short8 s0 = load_frag64(sb, ro0);            // kt=0, bias as C
    short8 s1 = load_frag64(sb, ro1);
#pragma unroll
    for (int mt = 0; mt < 2; ++mt) {
      acc[mt][0] = MFMA16(wfrag[mt][0], s0, bias[mt], 0, 0, 0);
      acc[mt][1] = MFMA16(wfrag[mt][0], s1, bias[mt], 0, 0, 0);
    }
#pragma unroll
    for (int kt = 1; kt < 4; ++kt) {
      s0 = load_frag64(sb, ro0 + kt * 32);
      s1 = load_frag64(sb, ro1 + kt * 32);
#pragma unroll
      for (int mt = 0; mt < 2; ++mt) {
        acc[mt][0] = MFMA16(wfrag[mt][kt], s0, acc[mt][0], 0, 0, 0);
        acc[mt][1] = MFMA16(wfrag[mt][kt], s1, acc[mt][1], 0, 0, 0);
      }
    }
#pragma unroll
    for (int mt = 0; mt < 2; ++mt) {
      acc[mt][0] = MFMA16(ufrag[mt], xf0, acc[mt][0], 0, 0, 0);
      acc[mt][1] = MFMA16(ufrag[mt], xf1, acc[mt][1], 0, 0, 0);
    }

    unsigned short* wp = &Sbuf[(t + 1) & 1][0];
#pragma unroll
    for (int mt = 0; mt < 2; ++mt) {
      f32x4 t0 = tanh4(acc[mt][0]);
      f32x4 t1 = tanh4(acc[mt][1]);
      uint2 e0; e0.x = pack2(t0[0], t0[1]); e0.y = pack2(t0[2], t0[3]);
      uint2 e1; e1.x = pack2(t1[0], t1[1]); e1.y = pack2(t1[2], t1[3]);
      *(uint2*)(wp + ro0 + dcol + mt * 16) = e0;
      *(uint2*)(wp + ro1 + dcol + mt * 16) = e1;
    }
    __syncthreads();
  };

  // ---- t = 0 (S=0: projection only), write Sbuf[1] ----
  {
    short8 xf0 = load_frag64(&Xbuf[0], xo0);
    short8 xf1 = load_frag64(&Xbuf[0], xo1);
    unsigned short* wp = &Sbuf[1][0];
#pragma unroll
    for (int mt = 0; mt < 2; ++mt) {
      f32x4 d0 = MFMA16(ufrag[mt], xf0, bias[mt], 0, 0, 0);
      f32x4 d1 = MFMA16(ufrag[mt], xf1, bias[mt], 0, 0, 0);
      f32x4 t0 = tanh4(d0);
      f32x4 t1 = tanh4(d1);
      uint2 e0; e0.x = pack2(t0[0], t0[1]); e0.y = pack2(t0[2], t0[3]);
      uint2 e1; e1.x = pack2(t1[0], t1[1]); e1.y = pack2(t1[2], t1[3]);
      *(uint2*)(wp + ro0 + dcol + mt * 16) = e0;
      *(uint2*)(wp + ro1 + dcol + mt * 16) = e1;
    }
  }
  __syncthreads();

  // ---- t = 1..9 on chunk 0 ----
#pragma unroll 1
  for (int t = 1; t < 10; ++t) step(t, t);

  // ---- restage chunk 1 (t = 10..19); chunk-0 reads done at step-9 barrier ----
  stage_chunk<10>(xblk, Xbuf, tid, 10);
  __syncthreads();
#pragma unroll 1
  for (int t = 10; t < 20; ++t) step(t, t - 10);

  // ---- restage chunk 2 (t = 20..27) ----
  stage_chunk<8>(xblk, Xbuf, tid, 20);
  __syncthreads();
#pragma unroll 1
  for (int t = 20; t < T_STEPS; ++t) step(t, t - 20);

  // ---- epilogue: out^T = Vw*S^T + Vb, 4-MFMA chain on waves 0,1 ----
  // Final S in Sbuf[(27+1)&1] = Sbuf[0].  Wave w handles batches w*16..+15.
  if (w < 2) {
    short8 vfrag[4];
    const float* vp = Vw + l15 * 128 + q * 8;
#pragma unroll
    for (int kt = 0; kt < 4; ++kt) {
      f32x4 v0 = zero4, v1 = zero4;
      if (l15 < 10) {
        v0 = *(const f32x4*)(vp + kt * 32);
        v1 = *(const f32x4*)(vp + kt * 32 + 4);
      }
      vfrag[kt] = to_frag(v0, v1);
    }
    const unsigned short* sp = &Sbuf[0][0] + (w * 16 + l15) * S_STRIDE + q * 8;
    f32x4 o;
#pragma unroll
    for (int r = 0; r < 4; ++r) {
      const int c = q * 4 + r;
      o[r] = (c < 10) ? Vb[c] : 0.f;
    }
#pragma unroll
    for (int kt = 0; kt < 4; ++kt)
      o = MFMA16(vfrag[kt], load_frag64(sp, kt * 32), o, 0, 0, 0);
#pragma unroll
    for (int r = 0; r < 4; ++r) {
      const int c = q * 4 + r;
      if (c < 10) out[(size_t)(b0 + w * 16 + l15) * 10 + c] = o[r];
    }
  }
}

extern "C" void kernel_launch(void* const* d_in, const int* in_sizes, int n_in,
                              void* d_out, int out_size, void* d_ws, size_t ws_size,
                              hipStream_t stream) {
  const float* x  = (const float*)d_in[0];
  const float* Uw = (const float*)d_in[1];
  const float* Ub = (const float*)d_in[2];
  const float* Ww = (const float*)d_in[3];
  const float* Wb = (const float*)d_in[4];
  const float* Vw = (const float*)d_in[5];
  const float* Vb = (const float*)d_in[6];
  rnn_fused<<<1024, 256, 0, stream>>>(x, Uw, Ub, Ww, Wb, Vw, Vb, (float*)d_out);
}

// Round 11
// 192.539 us; speedup vs baseline: 1.0232x; 1.0232x over previous
//
#include <hip/hip_runtime.h>

// SimpleRNN fused kernel for MI355X (gfx950).  B=32768, T=28, I=28, H=128, C=10.
//
// R17 = R15 (78.8 us, best measured) + critical-path surgery on the lockstep
// per-step chain.  Structure, staging, tanh, epilogue byte-identical to R15.
//   1. MFMA chain split 5 -> 2+3 (+1 f32x4 add): accA = w0*s0+bias -> w1*s1;
//      accB = u*xf+0 -> w2*s2 -> w3*s3; acc = accA+accB.  accB's first MFMA
//      has both operands IN REGS at barrier release (xf prefetched) -> matrix
//      pipe starts at cycle 0 instead of after ~120cy of ds_read wait.
//   2. xf prefetch: next step's x-frag loaded from read-only Xbuf BEFORE the
//      barrier; __syncthreads' lgkmcnt(0) drain completes it for free.
//   3. Two-phase loop with static Sbuf pointers (S1->S0; S0->S1): kills the
//      t&1 mux, ds offsets fold to immediates.
// Amortization ledger closed: R16 (clean retest, 32 batches/block) = 85 us >=
// R15's 78.8 -> work-per-barrier is dead.  Also dead: residency knobs
// (R11/R13), barrier-free state-in-regs (R8/R12), launch_bounds>4 (R10),
// pk-f32 asm tanh (R9), in-loop global x (R11/R14).
// Kill-criterion: dur >= 78 us clean => lockstep-recurrence latency floor;
// declare ceiling.
//
// MFMA 16x16x32 bf16 layouts (m89/m91):
//   A[m=lane&15][k=(lane>>4)*8+j]  B[k=(lane>>4)*8+j][n=lane&15]
//   D[(lane>>4)*4+r][lane&15]

#define T_STEPS 28
#define S_STRIDE 132
#define X_STRIDE 900
#define XSLOTS 3136          // 16 rows * 784 f32 / 4 per dwordx4

typedef __attribute__((ext_vector_type(4))) float f32x4;
typedef __attribute__((ext_vector_type(8))) short short8;

#define MFMA16 __builtin_amdgcn_mfma_f32_16x16x32_bf16

__device__ __forceinline__ unsigned pack2(float lo, float hi) {
#if __has_builtin(__builtin_amdgcn_cvt_pk_bf16_f32)
  auto p = __builtin_amdgcn_cvt_pk_bf16_f32(lo, hi);   // RNE pack, 1 inst
  return __builtin_bit_cast(unsigned, p);
#else
  unsigned a = __builtin_bit_cast(unsigned, lo);
  a += 0x7FFFu + ((a >> 16) & 1u);
  unsigned b = __builtin_bit_cast(unsigned, hi);
  b += 0x7FFFu + ((b >> 16) & 1u);
  return (a >> 16) | (b & 0xFFFF0000u);
#endif
}

__device__ __forceinline__ short8 to_frag(f32x4 a, f32x4 b) {
  union { unsigned u[4]; short8 v; } r;
  r.u[0] = pack2(a[0], a[1]);
  r.u[1] = pack2(a[2], a[3]);
  r.u[2] = pack2(b[0], b[1]);
  r.u[3] = pack2(b[2], b[3]);
  return r.v;
}

__device__ __forceinline__ short8 load_frag64(const unsigned short* sp, int off) {
  // two b64 reads; measured conflict-free at the stride-132 pattern (R1..R15)
  union { uint2 d[2]; short8 v; } r;
  r.d[0] = *(const uint2*)(sp + off);
  r.d[1] = *(const uint2*)(sp + off + 4);
  return r.v;
}

__device__ __forceinline__ float fast_exp2(float a) {
#if __has_builtin(__builtin_amdgcn_exp2f)
  return __builtin_amdgcn_exp2f(a);   // v_exp_f32
#else
  return __exp2f(a);
#endif
}

// tanh(x) = 1 - 2/(1 + e^{2x}); e^{2x} = 2^(x * 2*log2(e)).  5 insts/elem,
// saturates naturally, err ~1e-6.  (R15-proven: part of the -12 us step.)
__device__ __forceinline__ f32x4 tanh4(f32x4 z) {
  f32x4 t;
#pragma unroll
  for (int i = 0; i < 4; ++i) {
    float e = fast_exp2(z[i] * 2.885390081777927f);
    float r = __builtin_amdgcn_rcpf(1.0f + e);
    t[i] = __builtin_fmaf(r, -2.0f, 1.0f);
  }
  return t;
}

__global__ __launch_bounds__(256, 4) void rnn_fused(
    const float* __restrict__ x,  const float* __restrict__ Uw,
    const float* __restrict__ Ub, const float* __restrict__ Ww,
    const float* __restrict__ Wb, const float* __restrict__ Vw,
    const float* __restrict__ Vb, float* __restrict__ out) {
  __shared__ __align__(16) unsigned short Sbuf[2][16 * S_STRIDE];
  __shared__ __align__(16) unsigned short Xbuf[16 * X_STRIDE];

  const int tid  = threadIdx.x;
  const int w    = tid >> 6;
  const int lane = tid & 63;
  const int l15  = lane & 15;
  const int q    = lane >> 4;           // 0..3
  const int mrow = w * 32;              // h base for this wave (2 m-tiles)
  const int b0   = blockIdx.x * 16;

  const f32x4 zero4 = {0.f, 0.f, 0.f, 0.f};
  const float* xblk = x + (size_t)b0 * 784;

  // ---- prologue A: stage the whole x block -> Xbuf (bf16, k-padded) ----
  // slot s (dwordx4 of f32): global flat offset s*4 (fully coalesced).
  // LDS: row=s/196, g=s%196, t=g/7, j=g%7 -> row*900 + t*32 + j*4.
  {
    f32x4 xr[13];
#pragma unroll
    for (int k = 0; k < 13; ++k) {
      int s = tid + 256 * k;
      if (s < XSLOTS) xr[k] = *(const f32x4*)(xblk + s * 4);
    }
#pragma unroll
    for (int k = 0; k < 13; ++k) {
      int s = tid + 256 * k;
      if (s < XSLOTS) {
        int row = s / 196, g = s - row * 196, tt = g / 7, j = g - tt * 7;
        uint2 d; d.x = pack2(xr[k][0], xr[k][1]); d.y = pack2(xr[k][2], xr[k][3]);
        *(uint2*)(Xbuf + row * X_STRIDE + tt * 32 + j * 4) = d;
        if (j == 0) {   // zero k=28..31 once per (row,t)
          uint2 zz; zz.x = 0u; zz.y = 0u;
          *(uint2*)(Xbuf + row * X_STRIDE + tt * 32 + 28) = zz;
        }
      }
    }
  }

  // ---- prologue B: persistent weight fragments (after staging regs die) ----
  short8 wfrag[2][4];   // [mt][kt]
  short8 ufrag[2];      // [mt], K=32 padded (k>=28 zeroed)
  f32x4  bias[2];       // Ub[h]+Wb[h] at D rows h = mrow + mt*16 + q*4 + r
#pragma unroll
  for (int mt = 0; mt < 2; ++mt) {
    const int h = mrow + mt * 16 + l15;
    const float* wp = Ww + h * 128 + q * 8;
#pragma unroll
    for (int kt = 0; kt < 4; ++kt) {
      wfrag[mt][kt] = to_frag(*(const f32x4*)wp, *(const f32x4*)(wp + 4));
      wp += 32;
    }
    const float* up = Uw + h * 28 + q * 8;
    f32x4 u0 = *(const f32x4*)up;
    f32x4 u1 = zero4;
    if (q < 3) u1 = *(const f32x4*)(up + 4);
    ufrag[mt] = to_frag(u0, u1);
    const int hb = mrow + mt * 16 + q * 4;
    bias[mt] = *(const f32x4*)(Wb + hb) + *(const f32x4*)(Ub + hb);
  }
  __syncthreads();   // Xbuf visible

  const int ro = l15 * S_STRIDE;                 // S row base (batch = l15)
  const int xo = l15 * X_STRIDE + q * 8;         // x frag base

  // one step: read sbuf, write dbuf, optionally prefetch x-frag for tpre.
  // Split chains: accA (depth 2, bias C) + accB (depth 3, starts with u*xf
  // whose operands are already in regs at barrier release).
  auto stepx = [&](const unsigned short* sbuf, unsigned short* dbuf,
                   short8 xf, int tpre, short8* xpre) {
    const unsigned short* sp = sbuf + ro + q * 8;
    short8 s0 = load_frag64(sp, 0);
    short8 s1 = load_frag64(sp, 32);
    short8 s2 = load_frag64(sp, 64);
    short8 s3 = load_frag64(sp, 96);
    f32x4 aA[2], aB[2];
#pragma unroll
    for (int mt = 0; mt < 2; ++mt)
      aB[mt] = MFMA16(ufrag[mt], xf, zero4, 0, 0, 0);   // regs-only: starts now
#pragma unroll
    for (int mt = 0; mt < 2; ++mt) {
      aA[mt] = MFMA16(wfrag[mt][0], s0, bias[mt], 0, 0, 0);
      aA[mt] = MFMA16(wfrag[mt][1], s1, aA[mt], 0, 0, 0);
      aB[mt] = MFMA16(wfrag[mt][2], s2, aB[mt], 0, 0, 0);
      aB[mt] = MFMA16(wfrag[mt][3], s3, aB[mt], 0, 0, 0);
    }
    if (xpre) *xpre = load_frag64(&Xbuf[0], xo + tpre * 32);  // pre-barrier
#pragma unroll
    for (int mt = 0; mt < 2; ++mt) {
      f32x4 th = tanh4(aA[mt] + aB[mt]);
      uint2 dd; dd.x = pack2(th[0], th[1]); dd.y = pack2(th[2], th[3]);
      *(uint2*)(dbuf + ro + mrow + mt * 16 + q * 4) = dd;
    }
    __syncthreads();
  };

  // ---- t = 0 (S=0: projection only), write Sbuf[1]; prefetch xf(t=1) ----
  short8 xfA, xfB;
  {
    short8 xf = load_frag64(&Xbuf[0], xo);
    unsigned short* wp = &Sbuf[1][0];
#pragma unroll
    for (int mt = 0; mt < 2; ++mt) {
      f32x4 d0 = MFMA16(ufrag[mt], xf, bias[mt], 0, 0, 0);
      f32x4 t0 = tanh4(d0);
      uint2 dd; dd.x = pack2(t0[0], t0[1]); dd.y = pack2(t0[2], t0[3]);
      *(uint2*)(wp + ro + mrow + mt * 16 + q * 4) = dd;
    }
    xfA = load_frag64(&Xbuf[0], xo + 32);        // t=1, completes in the drain
  }
  __syncthreads();

  // ---- t = 1 .. 26 as 13 static-buffer pairs; t = 27 single ----
  // odd t: read Sbuf[1] -> write Sbuf[0]; even t: read Sbuf[0] -> write Sbuf[1]
#pragma unroll 1
  for (int t = 1; t < T_STEPS - 1; t += 2) {
    stepx(&Sbuf[1][0], &Sbuf[0][0], xfA, t + 1, &xfB);
    stepx(&Sbuf[0][0], &Sbuf[1][0], xfB, t + 2, &xfA);
  }
  stepx(&Sbuf[1][0], &Sbuf[0][0], xfA, 0, nullptr);   // t = 27 -> final in Sbuf[0]

  // ---- epilogue: out^T[c][b] = Vw*S^T + Vb as one 4-MFMA chain (wave 0) ----
  // Final S in Sbuf[0].  A = Vw rows c=l15 (<10, else 0); B = S^T read with
  // the step's exact S-frag pattern; D rows c = q*4+r, col b = l15.
  if (w == 0) {
    short8 vfrag[4];
    const float* vp = Vw + l15 * 128 + q * 8;
#pragma unroll
    for (int kt = 0; kt < 4; ++kt) {
      f32x4 v0 = zero4, v1 = zero4;
      if (l15 < 10) {
        v0 = *(const f32x4*)(vp + kt * 32);
        v1 = *(const f32x4*)(vp + kt * 32 + 4);
      }
      vfrag[kt] = to_frag(v0, v1);
    }
    const unsigned short* sp = &Sbuf[0][0] + ro + q * 8;
    f32x4 o;
#pragma unroll
    for (int r = 0; r < 4; ++r) {
      const int c = q * 4 + r;
      o[r] = (c < 10) ? Vb[c] : 0.f;
    }
#pragma unroll
    for (int kt = 0; kt < 4; ++kt)
      o = MFMA16(vfrag[kt], load_frag64(sp, kt * 32), o, 0, 0, 0);
#pragma unroll
    for (int r = 0; r < 4; ++r) {
      const int c = q * 4 + r;
      if (c < 10) out[(size_t)(b0 + l15) * 10 + c] = o[r];
    }
  }
}

extern "C" void kernel_launch(void* const* d_in, const int* in_sizes, int n_in,
                              void* d_out, int out_size, void* d_ws, size_t ws_size,
                              hipStream_t stream) {
  const float* x  = (const float*)d_in[0];
  const float* Uw = (const float*)d_in[1];
  const float* Ub = (const float*)d_in[2];
  const float* Ww = (const float*)d_in[3];
  const float* Wb = (const float*)d_in[4];
  const float* Vw = (const float*)d_in[5];
  const float* Vb = (const float*)d_in[6];
  rnn_fused<<<2048, 256, 0, stream>>>(x, Uw, Ub, Ww, Wb, Vw, Vb, (float*)d_out);
}

// Round 12
// 189.066 us; speedup vs baseline: 1.0420x; 1.0184x over previous
//
#include <hip/hip_runtime.h>

// SimpleRNN fused kernel for MI355X (gfx950).  B=32768, T=28, I=28, H=128, C=10.
//
// R18 = R15 verbatim (78.8 us dispatch / 190.4 us harness — best measured).
// Reverts R17's chain-split/prefetch surgery: measured +4 us (82.6-83.9 vs
// 78.8, disjoint ranges).  Hand-scheduling the 5-MFMA chain disturbed the
// compiler's own pipelining (guide m131-m141 lesson reproduced).
//
// Final-structure rationale (11-round ledger, all clean evidence):
//   - occupancy/residency knobs dead (R11/R13: occupancy pins ~36-40%)
//   - barrier-free state-in-regs dead (R8/R12: VGPR kills residency)
//   - work-per-barrier amortization dead (R14 confounded, R16 clean: 85>=78.8)
//   - in-loop global x dead (R11/R14: +15 us per-step vmcnt exposure)
//   - launch_bounds>4 dead (R10: allocator spills, 163 MB scratch)
//   - VALU cuts WIN (R15: exp2-tanh + MFMA epilogue, 91->78.8)
//   - critical-path hand-scheduling dead (R17: -4 us)
// The T=28 serial recurrence forces 27 barrier-synced LDS round-trips;
// counters at this point (VALUBusy 53, MfmaUtil 19, HBM 8%) = lockstep
// latency floor of the recurrence, the practical ceiling for this problem.
//
//   Structure (R7-lineage, all measured-proven):
//     - whole-x-block prologue staging -> Xbuf[16][900] bf16
//     - Sbuf[2][16*132] double-buffer, 4 waves, wave w owns h [32w,32w+32)
//     - __syncthreads per step (pure-LDS loop -> vmcnt drain free)
//     - bias-as-MFMA-C, 10 MFMA/wave/step, launch_bounds(256,4), grid 2048
//     - exp2 tanh: tanh(x) = 1 - 2/(1+e^{2x}), 5 insts/elem, err ~1e-6
//     - epilogue out^T = Vw*S^T + Vb as one 4-MFMA chain on wave 0
//
// MFMA 16x16x32 bf16 layouts (m89/m91):
//   A[m=lane&15][k=(lane>>4)*8+j]  B[k=(lane>>4)*8+j][n=lane&15]
//   D[(lane>>4)*4+r][lane&15]

#define T_STEPS 28
#define S_STRIDE 132
#define X_STRIDE 900
#define XSLOTS 3136          // 16 rows * 784 f32 / 4 per dwordx4

typedef __attribute__((ext_vector_type(4))) float f32x4;
typedef __attribute__((ext_vector_type(8))) short short8;

#define MFMA16 __builtin_amdgcn_mfma_f32_16x16x32_bf16

__device__ __forceinline__ unsigned pack2(float lo, float hi) {
#if __has_builtin(__builtin_amdgcn_cvt_pk_bf16_f32)
  auto p = __builtin_amdgcn_cvt_pk_bf16_f32(lo, hi);   // RNE pack, 1 inst
  return __builtin_bit_cast(unsigned, p);
#else
  unsigned a = __builtin_bit_cast(unsigned, lo);
  a += 0x7FFFu + ((a >> 16) & 1u);
  unsigned b = __builtin_bit_cast(unsigned, hi);
  b += 0x7FFFu + ((b >> 16) & 1u);
  return (a >> 16) | (b & 0xFFFF0000u);
#endif
}

__device__ __forceinline__ short8 to_frag(f32x4 a, f32x4 b) {
  union { unsigned u[4]; short8 v; } r;
  r.u[0] = pack2(a[0], a[1]);
  r.u[1] = pack2(a[2], a[3]);
  r.u[2] = pack2(b[0], b[1]);
  r.u[3] = pack2(b[2], b[3]);
  return r.v;
}

__device__ __forceinline__ short8 load_frag64(const unsigned short* sp, int off) {
  // two b64 reads; measured conflict-free at the stride-132-pattern (R1/R3/R5)
  union { uint2 d[2]; short8 v; } r;
  r.d[0] = *(const uint2*)(sp + off);
  r.d[1] = *(const uint2*)(sp + off + 4);
  return r.v;
}

__device__ __forceinline__ float fast_exp2(float a) {
#if __has_builtin(__builtin_amdgcn_exp2f)
  return __builtin_amdgcn_exp2f(a);   // v_exp_f32
#else
  return __exp2f(a);
#endif
}

// tanh(x) = 1 - 2/(1 + e^{2x}); e^{2x} = 2^(x * 2*log2(e)).
// 5 insts/elem (mul, exp, add, rcp, fma).  Saturates naturally:
// x>>0: exp=inf -> rcp=0 -> 1;  x<<0: exp=0 -> rcp(1)=1 -> -1.
__device__ __forceinline__ f32x4 tanh4(f32x4 z) {
  f32x4 t;
#pragma unroll
  for (int i = 0; i < 4; ++i) {
    float e = fast_exp2(z[i] * 2.885390081777927f);
    float r = __builtin_amdgcn_rcpf(1.0f + e);
    t[i] = __builtin_fmaf(r, -2.0f, 1.0f);
  }
  return t;
}

__global__ __launch_bounds__(256, 4) void rnn_fused(
    const float* __restrict__ x,  const float* __restrict__ Uw,
    const float* __restrict__ Ub, const float* __restrict__ Ww,
    const float* __restrict__ Wb, const float* __restrict__ Vw,
    const float* __restrict__ Vb, float* __restrict__ out) {
  __shared__ __align__(16) unsigned short Sbuf[2][16 * S_STRIDE];
  __shared__ __align__(16) unsigned short Xbuf[16 * X_STRIDE];

  const int tid  = threadIdx.x;
  const int w    = tid >> 6;
  const int lane = tid & 63;
  const int l15  = lane & 15;
  const int q    = lane >> 4;           // 0..3
  const int mrow = w * 32;              // h base for this wave (2 m-tiles)
  const int b0   = blockIdx.x * 16;

  const f32x4 zero4 = {0.f, 0.f, 0.f, 0.f};
  const float* xblk = x + (size_t)b0 * 784;

  // ---- prologue A: stage the whole x block -> Xbuf (bf16, k-padded) ----
  // slot s (dwordx4 of f32): global flat offset s*4 (fully coalesced).
  // LDS: row=s/196, g=s%196, t=g/7, j=g%7 -> row*900 + t*32 + j*4.
  {
    f32x4 xr[13];
#pragma unroll
    for (int k = 0; k < 13; ++k) {
      int s = tid + 256 * k;
      if (s < XSLOTS) xr[k] = *(const f32x4*)(xblk + s * 4);
    }
#pragma unroll
    for (int k = 0; k < 13; ++k) {
      int s = tid + 256 * k;
      if (s < XSLOTS) {
        int row = s / 196, g = s - row * 196, tt = g / 7, j = g - tt * 7;
        uint2 d; d.x = pack2(xr[k][0], xr[k][1]); d.y = pack2(xr[k][2], xr[k][3]);
        *(uint2*)(Xbuf + row * X_STRIDE + tt * 32 + j * 4) = d;
        if (j == 0) {   // zero k=28..31 once per (row,t)
          uint2 zz; zz.x = 0u; zz.y = 0u;
          *(uint2*)(Xbuf + row * X_STRIDE + tt * 32 + 28) = zz;
        }
      }
    }
  }

  // ---- prologue B: persistent weight fragments (after staging regs die) ----
  short8 wfrag[2][4];   // [mt][kt]
  short8 ufrag[2];      // [mt], K=32 padded (k>=28 zeroed)
  f32x4  bias[2];       // Ub[h]+Wb[h] at D rows h = mrow + mt*16 + q*4 + r
#pragma unroll
  for (int mt = 0; mt < 2; ++mt) {
    const int h = mrow + mt * 16 + l15;
    const float* wp = Ww + h * 128 + q * 8;
#pragma unroll
    for (int kt = 0; kt < 4; ++kt) {
      wfrag[mt][kt] = to_frag(*(const f32x4*)wp, *(const f32x4*)(wp + 4));
      wp += 32;
    }
    const float* up = Uw + h * 28 + q * 8;
    f32x4 u0 = *(const f32x4*)up;
    f32x4 u1 = zero4;
    if (q < 3) u1 = *(const f32x4*)(up + 4);
    ufrag[mt] = to_frag(u0, u1);
    const int hb = mrow + mt * 16 + q * 4;
    bias[mt] = *(const f32x4*)(Wb + hb) + *(const f32x4*)(Ub + hb);
  }
  __syncthreads();   // Xbuf visible

  const int ro = l15 * S_STRIDE;                 // S row base (batch = l15)
  const int xo = l15 * X_STRIDE + q * 8;         // x frag base
  f32x4 acc[2];

  // ---- t = 0 (S=0: projection only) ----
  {
    short8 xf = load_frag64(&Xbuf[0], xo);
    unsigned short* wp = &Sbuf[1][0];
#pragma unroll
    for (int mt = 0; mt < 2; ++mt) {
      f32x4 d0 = MFMA16(ufrag[mt], xf, bias[mt], 0, 0, 0);
      f32x4 t0 = tanh4(d0);
      uint2 dd; dd.x = pack2(t0[0], t0[1]); dd.y = pack2(t0[2], t0[3]);
      *(uint2*)(wp + ro + mrow + mt * 16 + q * 4) = dd;
    }
  }
  __syncthreads();

  // ---- t = 1 .. 27 : pure LDS/MFMA/VALU, zero global ----
#pragma unroll 1
  for (int t = 1; t < T_STEPS; ++t) {
    short8 xf = load_frag64(&Xbuf[0], xo + t * 32);

    const unsigned short* sp = &Sbuf[t & 1][0] + ro + q * 8;

    // kt = 0 with bias as C-operand
    short8 sA = load_frag64(sp, 0);
#pragma unroll
    for (int mt = 0; mt < 2; ++mt)
      acc[mt] = MFMA16(wfrag[mt][0], sA, bias[mt], 0, 0, 0);
#pragma unroll
    for (int kt = 1; kt < 4; ++kt) {
      sA = load_frag64(sp, kt * 32);
#pragma unroll
      for (int mt = 0; mt < 2; ++mt)
        acc[mt] = MFMA16(wfrag[mt][kt], sA, acc[mt], 0, 0, 0);
    }
#pragma unroll
    for (int mt = 0; mt < 2; ++mt)
      acc[mt] = MFMA16(ufrag[mt], xf, acc[mt], 0, 0, 0);

    unsigned short* wp = &Sbuf[(t + 1) & 1][0];
#pragma unroll
    for (int mt = 0; mt < 2; ++mt) {
      f32x4 th = tanh4(acc[mt]);
      uint2 dd; dd.x = pack2(th[0], th[1]); dd.y = pack2(th[2], th[3]);
      *(uint2*)(wp + ro + mrow + mt * 16 + q * 4) = dd;
    }
    __syncthreads();
  }

  // ---- epilogue: out^T[c][b] = Vw*S^T + Vb as one 4-MFMA chain (wave 0) ----
  // Final S in Sbuf[0].  A = Vw rows c=l15 (<10, else 0); B = S^T read with
  // the step's exact S-frag pattern; D rows c = q*4+r, col b = l15.
  if (w == 0) {
    short8 vfrag[4];
    const float* vp = Vw + l15 * 128 + q * 8;
#pragma unroll
    for (int kt = 0; kt < 4; ++kt) {
      f32x4 v0 = zero4, v1 = zero4;
      if (l15 < 10) {
        v0 = *(const f32x4*)(vp + kt * 32);
        v1 = *(const f32x4*)(vp + kt * 32 + 4);
      }
      vfrag[kt] = to_frag(v0, v1);
    }
    const unsigned short* sp = &Sbuf[0][0] + ro + q * 8;
    f32x4 o;
#pragma unroll
    for (int r = 0; r < 4; ++r) {
      const int c = q * 4 + r;
      o[r] = (c < 10) ? Vb[c] : 0.f;
    }
#pragma unroll
    for (int kt = 0; kt < 4; ++kt)
      o = MFMA16(vfrag[kt], load_frag64(sp, kt * 32), o, 0, 0, 0);
#pragma unroll
    for (int r = 0; r < 4; ++r) {
      const int c = q * 4 + r;
      if (c < 10) out[(size_t)(b0 + l15) * 10 + c] = o[r];
    }
  }
}

extern "C" void kernel_launch(void* const* d_in, const int* in_sizes, int n_in,
                              void* d_out, int out_size, void* d_ws, size_t ws_size,
                              hipStream_t stream) {
  const float* x  = (const float*)d_in[0];
  const float* Uw = (const float*)d_in[1];
  const float* Ub = (const float*)d_in[2];
  const float* Ww = (const float*)d_in[3];
  const float* Wb = (const float*)d_in[4];
  const float* Vw = (const float*)d_in[5];
  const float* Vb = (const float*)d_in[6];
  rnn_fused<<<2048, 256, 0, stream>>>(x, Uw, Ub, Ww, Wb, Vw, Vb, (float*)d_out);
}